// Round 4
// baseline (4387.492 us; speedup 1.0000x reference)
//
#include <hip/hip_runtime.h>
#include <hip/hip_bf16.h>

typedef __hip_bfloat16 bf16;
typedef __attribute__((ext_vector_type(8))) short bf16x8s;
typedef __attribute__((ext_vector_type(4))) float f32x4;

#define NB 64
#define NS 32
#define NV 10000
#define NE 512
#define NH 512
#define NF 2048
#define ND 1024
#define G_WGS 32

static __device__ __forceinline__ float bf2f(bf16 x) { return __bfloat162float(x); }
static __device__ __forceinline__ bf16 f2bf(float x) { return __float2bfloat16(x); }
static __device__ __forceinline__ f32x4 mfma16(bf16x8s a, bf16x8s b, f32x4 c) {
  return __builtin_amdgcn_mfma_f32_16x16x32_bf16(a, b, c, 0, 0, 0);
}

// ---- agent-coherent (cross-XCD, LLC-level) accesses: no cache maintenance needed ----
static __device__ __forceinline__ float ld_agent(const float* p) {
  return __hip_atomic_load(const_cast<float*>(p), __ATOMIC_RELAXED, __HIP_MEMORY_SCOPE_AGENT);
}
static __device__ __forceinline__ void st_agent(float* p, float v) {
  __hip_atomic_store(p, v, __ATOMIC_RELAXED, __HIP_MEMORY_SCOPE_AGENT);
}
static __device__ __forceinline__ unsigned ldu_agent(unsigned* p) {
  return __hip_atomic_load(p, __ATOMIC_RELAXED, __HIP_MEMORY_SCOPE_AGENT);
}
static __device__ __forceinline__ short bfbits(float x) { bf16 h = f2bf(x); return *(short*)&h; }
// 8 consecutive f32 via agent loads -> bf16 MFMA fragment
static __device__ __forceinline__ bf16x8s ldfrag_agent(const float* p) {
  bf16x8s r;
#pragma unroll
  for (int i = 0; i < 8; i++) r[i] = bfbits(ld_agent(p + i));
  return r;
}

// One 16x16 output tile per wave. A row-major bf16 [*, lda], BT row-major bf16 [N][K].
// mfma_f32_16x16x32_bf16: A row=lane&15, k=(lane>>4)*8+j ; C/D col=lane&15, row=(lane>>4)*4+j
__device__ __forceinline__ f32x4 wave_tile16(const bf16* A, const bf16* BT,
                                             int lda, int K, int m0, int n0) {
  int lane = threadIdx.x & 63;
  int r = lane & 15, g = lane >> 4;
  const bf16* ap = A + (size_t)(m0 + r) * lda + g * 8;
  const bf16* bp = BT + (size_t)(n0 + r) * K + g * 8;
  f32x4 acc = {0.f, 0.f, 0.f, 0.f};
#pragma unroll 4
  for (int k = 0; k < K; k += 32) {
    bf16x8s a = *(const bf16x8s*)(ap + k);
    bf16x8s b = *(const bf16x8s*)(bp + k);
    acc = mfma16(a, b, acc);
  }
  return acc;
}

// ---------------- embedding gather + f32->bf16 ----------------
__global__ void k_embed(const int* __restrict__ tokens, const float* __restrict__ emb,
                        bf16* __restrict__ x0) {
  int row = blockIdx.x;            // 0..2047
  int tok = tokens[row];
  const float2* src = (const float2*)(emb + (size_t)tok * NE);
  uint32_t* dst = (uint32_t*)(x0 + (size_t)row * NE);
  float2 v = src[threadIdx.x];
  __hip_bfloat162 p;
  p.x = f2bf(v.x); p.y = f2bf(v.y);
  dst[threadIdx.x] = *(uint32_t*)&p;
}

// ---------------- f32->bf16 convert (contiguous) ----------------
__global__ void k_cvt(const float* __restrict__ src, bf16* __restrict__ dst, int n) {
  int i = blockIdx.x * 256 + threadIdx.x;
  if (i < n) dst[i] = f2bf(src[i]);
}

// ---------------- transpose + f32->bf16: dst[n][k] = bf16(src[k][n]) ----------------
__global__ void k_transpose(const float* __restrict__ src, bf16* __restrict__ dst,
                            int K, int N) {
  __shared__ float tile[32][33];
  int n0 = blockIdx.x * 32, k0 = blockIdx.y * 32;
  int tx = threadIdx.x & 31, ty = threadIdx.x >> 5;   // 32x8
  for (int i = ty; i < 32; i += 8) {
    int k = k0 + i, n = n0 + tx;
    tile[i][tx] = (k < K && n < N) ? src[(size_t)k * N + n] : 0.f;
  }
  __syncthreads();
  for (int i = ty; i < 32; i += 8) {
    int n = n0 + i, k = k0 + tx;
    if (n < N && k < K) dst[(size_t)n * K + k] = f2bf(tile[tx][i]);
  }
}

// ---------------- fused 12x [512,512] layer-weight transposes ----------------
__global__ void k_transpose12(const float* __restrict__ w_r, const float* __restrict__ w_u,
                              const float* __restrict__ w_h, bf16* __restrict__ ruhT,
                              bf16* __restrict__ hhT, bf16* __restrict__ xT) {
  int z = blockIdx.z, l = z / 6, q = z % 6;
  const float* srcs[6] = {
    w_r + (size_t)l * ND * NH + (size_t)512 * NH,
    w_u + (size_t)l * ND * NH + (size_t)512 * NH,
    w_h + (size_t)l * ND * NH + (size_t)512 * NH,
    w_r + (size_t)l * ND * NH,
    w_u + (size_t)l * ND * NH,
    w_h + (size_t)l * ND * NH };
  bf16* dsts[6] = {
    ruhT + (size_t)l * 1024 * 512,
    ruhT + (size_t)l * 1024 * 512 + 512 * 512,
    hhT  + (size_t)l * 512 * 512,
    xT   + (size_t)l * 1536 * 512,
    xT   + (size_t)l * 1536 * 512 + 512 * 512,
    xT   + (size_t)l * 1536 * 512 + 1024 * 512 };
  const float* src = srcs[q];
  bf16* dst = dsts[q];
  __shared__ float tile[32][33];
  int n0 = blockIdx.x * 32, k0 = blockIdx.y * 32;
  int tx = threadIdx.x & 31, ty = threadIdx.x >> 5;
  for (int i = ty; i < 32; i += 8)
    tile[i][tx] = src[(size_t)(k0 + i) * NH + n0 + tx];
  __syncthreads();
  for (int i = ty; i < 32; i += 8)
    dst[(size_t)(n0 + i) * NH + k0 + tx] = f2bf(tile[tx][i]);
}

// ---------------- both layers' gate biases -> bias3[2][1536] f32 ----------------
__global__ void k_bias3all(const float* __restrict__ br, const float* __restrict__ bu,
                           const float* __restrict__ bh, float* __restrict__ bias) {
  int i = blockIdx.x * 256 + threadIdx.x;
  if (i < 3072) {
    int l = i / 1536, c = i % 1536;
    const float* s = (c < 512) ? (br + l * 512 + c)
                   : (c < 1024 ? (bu + l * 512 + (c - 512)) : (bh + l * 512 + (c - 1024)));
    bias[i] = *s;
  }
}

// ---------------- h0 = cnn @ w_in + b_in : [64,2048]@[2048,512] -> f32 ----------------
__global__ void k_gemm_h0(const bf16* __restrict__ A, const bf16* __restrict__ BT,
                          const float* __restrict__ bias, float* __restrict__ h0f) {
  int wid = blockIdx.x * 4 + (threadIdx.x >> 6);  // 128 waves: 4 x 32 tiles
  int mt = wid & 3, nt = wid >> 2;
  f32x4 acc = wave_tile16(A, BT, NF, NF, mt * 16, nt * 16);
  int lane = threadIdx.x & 63;
  int cl = lane & 15, g = lane >> 4;
  int col = nt * 16 + cl;
  float bv = bias[col];
#pragma unroll
  for (int j = 0; j < 4; j++) {
    int row = mt * 16 + g * 4 + j;
    h0f[(size_t)row * NH + col] = acc[j] + bv;
  }
}

// ---------------- pre = X @ Wx_cat + bias3 : [2048,512]@[512,1536] -> f32 ----------------
__global__ void k_gemm_pre(const bf16* __restrict__ A, const bf16* __restrict__ BT,
                           const float* __restrict__ bias, float* __restrict__ pre) {
  int wid = (blockIdx.x * blockDim.x + threadIdx.x) >> 6;  // 12288 waves: 128 x 96 tiles
  int mt = wid % 128, nt = wid / 128;
  f32x4 acc = wave_tile16(A, BT, NE, NE, mt * 16, nt * 16);
  int lane = threadIdx.x & 63;
  int cl = lane & 15, g = lane >> 4;
  int col = nt * 16 + cl;
  float bv = bias[col];
#pragma unroll
  for (int j = 0; j < 4; j++) {
    int row = mt * 16 + g * 4 + j;
    pre[(size_t)row * 1536 + col] = acc[j] + bv;
  }
}

// ---------------- lightweight device barrier: NO cache maintenance ----------------
// Correct because ALL cross-WG data moves via agent-scope (sc-bit, LLC-coherent)
// atomics; vmcnt(0) guarantees this wave's sc-stores are ack'd at the LLC before
// arrival; consumer loads issue only after the poll load returns the target value.
static __device__ __forceinline__ void gbar(unsigned* cnt, unsigned ep) {
  asm volatile("s_waitcnt vmcnt(0)" ::: "memory");   // per-wave: drain sc-stores
  __syncthreads();
  if (threadIdx.x == 0) {
    atomicAdd(cnt, 1u);                              // device-scope arrive (LLC)
    while (ldu_agent(cnt) < G_WGS * ep) __builtin_amdgcn_s_sleep(2);
  }
  __syncthreads();
  asm volatile("" ::: "memory");                     // no hoisting loads above barrier
}

// ---------------- persistent per-layer GRU recurrence ----------------
// 32 WGs x 512 thr = 256 waves, all co-resident. Phase1: r,u gates [64,1024];
// Phase2 (waves 0..127): h_tilde + combine. Weights register-resident.
// Cross-WG state (hf, rh_f, u_f) only ever touched via agent atomics.
__global__ __launch_bounds__(512, 1)
void k_gru_layer(const bf16* __restrict__ W_ruh_T, const bf16* __restrict__ W_hh_T,
                 const float* __restrict__ pre,
                 float* __restrict__ hf, float* __restrict__ rh_f,
                 float* __restrict__ u_f, bf16* __restrict__ seq,
                 unsigned* __restrict__ barcnt) {
  const int lane = threadIdx.x & 63;
  const int w = blockIdx.x * 8 + (threadIdx.x >> 6);   // 0..255
  const int cl = lane & 15, g = lane >> 4;
  const int mt = w & 3, nt = w >> 2;                   // phase1 tile (nt 0..63)
  const int col = nt * 16 + cl;

  // register-resident weight B-fragments (reused all 32 steps)
  bf16x8s bw1[16];
  { const bf16* bp = W_ruh_T + (size_t)col * NH + g * 8;
#pragma unroll
    for (int k = 0; k < 16; k++) bw1[k] = *(const bf16x8s*)(bp + k * 32); }
  bf16x8s bw2[16];
  if (w < 128) {
    const bf16* bp = W_hh_T + (size_t)col * NH + g * 8;
#pragma unroll
    for (int k = 0; k < 16; k++) bw2[k] = *(const bf16x8s*)(bp + k * 32);
  }
  // this thread's own h[b][col] slots (phase2 tiles cover all 64x512 of h)
  float h_reg[4];
  if (w < 128) {
#pragma unroll
    for (int j = 0; j < 4; j++) h_reg[j] = hf[(size_t)(mt * 16 + g * 4 + j) * NH + col];
  }

  unsigned ep = 0;
  for (int t = 0; t < NS; t++) {
    { // ---- phase 1: r (w<128) / u (w>=128) gates
      const float* ap = hf + (size_t)(mt * 16 + cl) * NH + g * 8;
      f32x4 acc0 = {0.f,0.f,0.f,0.f}, acc1 = {0.f,0.f,0.f,0.f};
#pragma unroll
      for (int k = 0; k < 16; k += 2) {
        acc0 = mfma16(ldfrag_agent(ap + k * 32),       bw1[k],     acc0);
        acc1 = mfma16(ldfrag_agent(ap + (k + 1) * 32), bw1[k + 1], acc1);
      }
#pragma unroll
      for (int j = 0; j < 4; j++) {
        int b = mt * 16 + g * 4 + j;
        float pv = pre[(size_t)(b * NS + t) * 1536 + col];
        float gate = 1.f / (1.f + expf(-(acc0[j] + acc1[j] + pv)));
        if (w < 128) st_agent(&rh_f[b * NH + col], gate * h_reg[j]);
        else         st_agent(&u_f[b * NH + (col - 512)], gate);
      }
    }
    gbar(barcnt, ++ep);
    if (w < 128) { // ---- phase 2: h_tilde + combine
      const float* ap = rh_f + (size_t)(mt * 16 + cl) * NH + g * 8;
      f32x4 acc0 = {0.f,0.f,0.f,0.f}, acc1 = {0.f,0.f,0.f,0.f};
#pragma unroll
      for (int k = 0; k < 16; k += 2) {
        acc0 = mfma16(ldfrag_agent(ap + k * 32),       bw2[k],     acc0);
        acc1 = mfma16(ldfrag_agent(ap + (k + 1) * 32), bw2[k + 1], acc1);
      }
#pragma unroll
      for (int j = 0; j < 4; j++) {
        int b = mt * 16 + g * 4 + j;
        float pv = pre[(size_t)(b * NS + t) * 1536 + 1024 + col];
        float htil = tanhf(acc0[j] + acc1[j] + pv);
        float u = ld_agent(&u_f[b * NH + col]);
        float hnew = h_reg[j] * u + (1.f - u) * htil;
        h_reg[j] = hnew;
        st_agent(&hf[b * NH + col], hnew);
        seq[(size_t)(b * NS + t) * NH + col] = f2bf(hnew);
      }
    }
    gbar(barcnt, ++ep);
  }
}

// ---------------- logits = seq1 @ w_out + b_out : [2048,512]@[512,10000] -> f32 ---------
__global__ void k_gemm_out(const bf16* __restrict__ A, const bf16* __restrict__ BT,
                           const float* __restrict__ bias, float* __restrict__ out) {
  int wid = blockIdx.x * 4 + (threadIdx.x >> 6);  // 32 * 157 = 5024 waves
  int mg = wid % 32, ng = wid / 32;
  int lane = threadIdx.x & 63;
  int cl = lane & 15, g = lane >> 4;
  f32x4 acc[4][4] = {};
  const bf16* a0 = A + (size_t)(mg * 64 + cl) * NE + g * 8;
  const bf16* b0 = BT + (size_t)(ng * 64 + cl) * NE + g * 8;
#pragma unroll 2
  for (int k = 0; k < NE; k += 32) {
    bf16x8s av[4], bv[4];
#pragma unroll
    for (int i = 0; i < 4; i++) av[i] = *(const bf16x8s*)(a0 + (size_t)(i * 16) * NE + k);
#pragma unroll
    for (int i = 0; i < 4; i++) bv[i] = *(const bf16x8s*)(b0 + (size_t)(i * 16) * NE + k);
#pragma unroll
    for (int mi = 0; mi < 4; mi++)
#pragma unroll
      for (int ni = 0; ni < 4; ni++)
        acc[mi][ni] = mfma16(av[mi], bv[ni], acc[mi][ni]);
  }
#pragma unroll
  for (int mi = 0; mi < 4; mi++) {
#pragma unroll
    for (int ni = 0; ni < 4; ni++) {
      int colb = ng * 64 + ni * 16 + cl;
      if (colb < NV) {
        float bv2 = bias[colb];
#pragma unroll
        for (int j = 0; j < 4; j++) {
          int row = mg * 64 + mi * 16 + g * 4 + j;
          out[(size_t)row * NV + colb] = acc[mi][ni][j] + bv2;
        }
      }
    }
  }
}

extern "C" void kernel_launch(void* const* d_in, const int* in_sizes, int n_in,
                              void* d_out, int out_size, void* d_ws, size_t ws_size,
                              hipStream_t stream) {
  const int*   tokens = (const int*)d_in[0];
  const float* cnn    = (const float*)d_in[1];
  const float* emb    = (const float*)d_in[2];
  const float* w_in   = (const float*)d_in[3];
  const float* b_in   = (const float*)d_in[4];
  const float* w_r    = (const float*)d_in[5];
  const float* b_r    = (const float*)d_in[6];
  const float* w_u    = (const float*)d_in[7];
  const float* b_u    = (const float*)d_in[8];
  const float* w_h    = (const float*)d_in[9];
  const float* b_h    = (const float*)d_in[10];
  const float* w_out  = (const float*)d_in[11];
  const float* b_out  = (const float*)d_in[12];
  float* out = (float*)d_out;

  // ---- workspace carve-up (bytes), 256B aligned ----
  char* ws = (char*)d_ws;
  size_t off = 0;
  auto alloc = [&](size_t bytes) { char* p = ws + off; off += (bytes + 255) & ~(size_t)255; return p; };
  bf16*  x0      = (bf16*) alloc((size_t)2048 * 512 * 2);
  bf16*  seq0    = (bf16*) alloc((size_t)2048 * 512 * 2);
  bf16*  seq1    = (bf16*) alloc((size_t)2048 * 512 * 2);
  float* pre     = (float*)alloc((size_t)2048 * 1536 * 4);
  float* h0f     = (float*)alloc((size_t)64 * 512 * 4);
  float* hf      = (float*)alloc((size_t)64 * 512 * 4);
  float* rh_f    = (float*)alloc((size_t)64 * 512 * 4);
  float* u_f     = (float*)alloc((size_t)64 * 512 * 4);
  float* bias3   = (float*)alloc((size_t)2 * 1536 * 4);
  bf16*  cnn_b   = (bf16*) alloc((size_t)64 * 2048 * 2);
  bf16*  w_in_T  = (bf16*) alloc((size_t)512 * 2048 * 2);
  bf16*  w_ruh_T = (bf16*) alloc((size_t)2 * 1024 * 512 * 2);   // per layer: [1024][512]
  bf16*  w_hh_T  = (bf16*) alloc((size_t)2 * 512 * 512 * 2);    // per layer: [512][512]
  bf16*  w_x_T   = (bf16*) alloc((size_t)2 * 1536 * 512 * 2);   // per layer: [1536][512]
  bf16*  w_out_T = (bf16*) alloc((size_t)10048 * 512 * 2);      // padded to 10048 rows
  unsigned* barcnt = (unsigned*)alloc(256);                     // [0]=layer0, [1]=layer1
  (void)ws_size; (void)in_sizes; (void)n_in; (void)out_size;

  // zero barrier counters + w_out_T pad rows (fresh every launch: graph-replay safe)
  hipMemsetAsync(barcnt, 0, 256, stream);
  hipMemsetAsync(w_out_T + (size_t)10000 * 512, 0, (size_t)48 * 512 * 2, stream);

  // ---- embedding gather (+convert) ----
  k_embed<<<2048, 256, 0, stream>>>(tokens, emb, x0);

  // ---- input converts / weight transposes (f32 -> bf16) ----
  k_cvt<<<512, 256, 0, stream>>>(cnn, cnn_b, 64 * 2048);
  k_transpose<<<dim3(16, 64), 256, 0, stream>>>(w_in, w_in_T, NF, NH);   // [2048,512]->[512][2048]
  k_transpose12<<<dim3(16, 16, 12), 256, 0, stream>>>(w_r, w_u, w_h, w_ruh_T, w_hh_T, w_x_T);
  k_transpose<<<dim3(313, 16), 256, 0, stream>>>(w_out, w_out_T, 512, NV);
  k_bias3all<<<12, 256, 0, stream>>>(b_r, b_u, b_h, bias3);

  // ---- h0 ----
  k_gemm_h0<<<32, 256, 0, stream>>>(cnn_b, w_in_T, b_in, h0f);

  // ---- per-layer: x-part GEMM, then fused persistent recurrence ----
  const bf16* seq_in[2] = {x0, seq0};
  bf16* seq_out[2] = {seq0, seq1};
  for (int l = 0; l < 2; l++) {
    k_gemm_pre<<<3072, 256, 0, stream>>>(seq_in[l], w_x_T + (size_t)l * 1536 * 512,
                                         bias3 + (size_t)l * 1536, pre);
    hipMemcpyAsync(hf, h0f, (size_t)64 * 512 * 4, hipMemcpyDeviceToDevice, stream);
    k_gru_layer<<<G_WGS, 512, 0, stream>>>(w_ruh_T + (size_t)l * 1024 * 512,
                                           w_hh_T + (size_t)l * 512 * 512,
                                           pre, hf, rh_f, u_f, seq_out[l], barcnt + l);
  }

  // ---- logits ----
  k_gemm_out<<<1256, 256, 0, stream>>>(seq1, w_out_T, b_out, out);
}

// Round 5
// 1565.301 us; speedup vs baseline: 2.8030x; 2.8030x over previous
//
#include <hip/hip_runtime.h>
#include <hip/hip_bf16.h>

typedef __hip_bfloat16 bf16;
typedef __attribute__((ext_vector_type(8))) short bf16x8s;
typedef __attribute__((ext_vector_type(4))) float f32x4;
typedef __attribute__((ext_vector_type(4))) int i32x4;

#define NB 64
#define NS 32
#define NV 10000
#define NE 512
#define NH 512
#define NF 2048
#define ND 1024
#define G_WGS 32

static __device__ __forceinline__ float bf2f(bf16 x) { return __bfloat162float(x); }
static __device__ __forceinline__ bf16 f2bf(float x) { return __float2bfloat16(x); }
static __device__ __forceinline__ f32x4 mfma16(bf16x8s a, bf16x8s b, f32x4 c) {
  return __builtin_amdgcn_mfma_f32_16x16x32_bf16(a, b, c, 0, 0, 0);
}

// ---- LLC-coherent (cross-XCD) vector accesses: bypass per-XCD L1/L2 via sc0 sc1.
// NOTE: compiler does NOT track vmcnt for these — caller must s_waitcnt before use.
static __device__ __forceinline__ i32x4 ld16_sc(const void* p) {
  i32x4 r;
  asm volatile("global_load_dwordx4 %0, %1, off sc0 sc1" : "=v"(r) : "v"(p) : "memory");
  return r;
}
static __device__ __forceinline__ unsigned ldus_sc(const void* p) {
  unsigned r;
  asm volatile("global_load_ushort %0, %1, off sc0 sc1" : "=v"(r) : "v"(p) : "memory");
  return r;
}
static __device__ __forceinline__ void stus_sc(void* p, unsigned v) {
  asm volatile("global_store_short %0, %1, off sc0 sc1" :: "v"(p), "v"(v) : "memory");
}
static __device__ __forceinline__ void wait_vm0() {
  asm volatile("s_waitcnt vmcnt(0)" ::: "memory");
  __builtin_amdgcn_sched_barrier(0);                 // rule #18: pin MFMA after the wait
}

// One 16x16 output tile per wave (cached path, for the plain GEMMs).
__device__ __forceinline__ f32x4 wave_tile16(const bf16* A, const bf16* BT,
                                             int lda, int K, int m0, int n0) {
  int lane = threadIdx.x & 63;
  int r = lane & 15, g = lane >> 4;
  const bf16* ap = A + (size_t)(m0 + r) * lda + g * 8;
  const bf16* bp = BT + (size_t)(n0 + r) * K + g * 8;
  f32x4 acc = {0.f, 0.f, 0.f, 0.f};
#pragma unroll 4
  for (int k = 0; k < K; k += 32) {
    bf16x8s a = *(const bf16x8s*)(ap + k);
    bf16x8s b = *(const bf16x8s*)(bp + k);
    acc = mfma16(a, b, acc);
  }
  return acc;
}

// ---------------- embedding gather + f32->bf16 ----------------
__global__ void k_embed(const int* __restrict__ tokens, const float* __restrict__ emb,
                        bf16* __restrict__ x0) {
  int row = blockIdx.x;
  int tok = tokens[row];
  const float2* src = (const float2*)(emb + (size_t)tok * NE);
  uint32_t* dst = (uint32_t*)(x0 + (size_t)row * NE);
  float2 v = src[threadIdx.x];
  __hip_bfloat162 p;
  p.x = f2bf(v.x); p.y = f2bf(v.y);
  dst[threadIdx.x] = *(uint32_t*)&p;
}

__global__ void k_cvt(const float* __restrict__ src, bf16* __restrict__ dst, int n) {
  int i = blockIdx.x * 256 + threadIdx.x;
  if (i < n) dst[i] = f2bf(src[i]);
}

__global__ void k_transpose(const float* __restrict__ src, bf16* __restrict__ dst,
                            int K, int N) {
  __shared__ float tile[32][33];
  int n0 = blockIdx.x * 32, k0 = blockIdx.y * 32;
  int tx = threadIdx.x & 31, ty = threadIdx.x >> 5;
  for (int i = ty; i < 32; i += 8) {
    int k = k0 + i, n = n0 + tx;
    tile[i][tx] = (k < K && n < N) ? src[(size_t)k * N + n] : 0.f;
  }
  __syncthreads();
  for (int i = ty; i < 32; i += 8) {
    int n = n0 + i, k = k0 + tx;
    if (n < N && k < K) dst[(size_t)n * K + k] = f2bf(tile[tx][i]);
  }
}

__global__ void k_transpose12(const float* __restrict__ w_r, const float* __restrict__ w_u,
                              const float* __restrict__ w_h, bf16* __restrict__ ruhT,
                              bf16* __restrict__ hhT, bf16* __restrict__ xT) {
  int z = blockIdx.z, l = z / 6, q = z % 6;
  const float* srcs[6] = {
    w_r + (size_t)l * ND * NH + (size_t)512 * NH,
    w_u + (size_t)l * ND * NH + (size_t)512 * NH,
    w_h + (size_t)l * ND * NH + (size_t)512 * NH,
    w_r + (size_t)l * ND * NH,
    w_u + (size_t)l * ND * NH,
    w_h + (size_t)l * ND * NH };
  bf16* dsts[6] = {
    ruhT + (size_t)l * 1024 * 512,
    ruhT + (size_t)l * 1024 * 512 + 512 * 512,
    hhT  + (size_t)l * 512 * 512,
    xT   + (size_t)l * 1536 * 512,
    xT   + (size_t)l * 1536 * 512 + 512 * 512,
    xT   + (size_t)l * 1536 * 512 + 1024 * 512 };
  const float* src = srcs[q];
  bf16* dst = dsts[q];
  __shared__ float tile[32][33];
  int n0 = blockIdx.x * 32, k0 = blockIdx.y * 32;
  int tx = threadIdx.x & 31, ty = threadIdx.x >> 5;
  for (int i = ty; i < 32; i += 8)
    tile[i][tx] = src[(size_t)(k0 + i) * NH + n0 + tx];
  __syncthreads();
  for (int i = ty; i < 32; i += 8)
    dst[(size_t)(n0 + i) * NH + k0 + tx] = f2bf(tile[tx][i]);
}

__global__ void k_bias3all(const float* __restrict__ br, const float* __restrict__ bu,
                           const float* __restrict__ bh, float* __restrict__ bias) {
  int i = blockIdx.x * 256 + threadIdx.x;
  if (i < 3072) {
    int l = i / 1536, c = i % 1536;
    const float* s = (c < 512) ? (br + l * 512 + c)
                   : (c < 1024 ? (bu + l * 512 + (c - 512)) : (bh + l * 512 + (c - 1024)));
    bias[i] = *s;
  }
}

// ---------------- h0 = cnn @ w_in + b_in, dual-store f32 + bf16 ----------------
__global__ void k_gemm_h0(const bf16* __restrict__ A, const bf16* __restrict__ BT,
                          const float* __restrict__ bias,
                          float* __restrict__ h0f, bf16* __restrict__ h0b) {
  int wid = blockIdx.x * 4 + (threadIdx.x >> 6);
  int mt = wid & 3, nt = wid >> 2;
  f32x4 acc = wave_tile16(A, BT, NF, NF, mt * 16, nt * 16);
  int lane = threadIdx.x & 63;
  int cl = lane & 15, g = lane >> 4;
  int col = nt * 16 + cl;
  float bv = bias[col];
#pragma unroll
  for (int j = 0; j < 4; j++) {
    int row = mt * 16 + g * 4 + j;
    float v = acc[j] + bv;
    h0f[(size_t)row * NH + col] = v;
    h0b[(size_t)row * NH + col] = f2bf(v);
  }
}

__global__ void k_gemm_pre(const bf16* __restrict__ A, const bf16* __restrict__ BT,
                           const float* __restrict__ bias, float* __restrict__ pre) {
  int wid = (blockIdx.x * blockDim.x + threadIdx.x) >> 6;
  int mt = wid % 128, nt = wid / 128;
  f32x4 acc = wave_tile16(A, BT, NE, NE, mt * 16, nt * 16);
  int lane = threadIdx.x & 63;
  int cl = lane & 15, g = lane >> 4;
  int col = nt * 16 + cl;
  float bv = bias[col];
#pragma unroll
  for (int j = 0; j < 4; j++) {
    int row = mt * 16 + g * 4 + j;
    pre[(size_t)row * 1536 + col] = acc[j] + bv;
  }
}

// ---------------- device barrier: no cache maintenance (all shared data is sc-path) ----
static __device__ __forceinline__ void gbar(unsigned* cnt, unsigned ep) {
  asm volatile("s_waitcnt vmcnt(0)" ::: "memory");   // sc-stores ack'd at LLC
  __syncthreads();
  if (threadIdx.x == 0) {
    atomicAdd(cnt, 1u);                              // device-scope (LLC) arrive
    while (__hip_atomic_load(cnt, __ATOMIC_RELAXED, __HIP_MEMORY_SCOPE_AGENT) < G_WGS * ep)
      __builtin_amdgcn_s_sleep(2);
  }
  __syncthreads();
  __builtin_amdgcn_sched_barrier(0);
  asm volatile("" ::: "memory");
}

// ---------------- persistent per-layer GRU recurrence ----------------
// 32 WGs x 512 thr = 256 waves, co-resident. Waves 0..127 ("u-waves"): phase1 u-gate
// (kept in regs), phase2 h_tilde+combine (h kept in regs). Waves 128..255 ("r-waves"):
// phase1 r-gate -> rh store. Cross-WG state (hb, rh_b) is bf16 moved ONLY via sc0sc1
// vector ops; barrier needs no L2 writeback/invalidate.
__global__ __launch_bounds__(512, 1)
void k_gru_layer(const bf16* __restrict__ W_ruh_T, const bf16* __restrict__ W_hh_T,
                 const float* __restrict__ pre, const float* __restrict__ h0f,
                 bf16* __restrict__ hb, bf16* __restrict__ rh_b,
                 bf16* __restrict__ seq, unsigned* __restrict__ barcnt) {
  const int lane = threadIdx.x & 63;
  const int w = blockIdx.x * 8 + (threadIdx.x >> 6);   // 0..255
  const int cl = lane & 15, g = lane >> 4;
  const bool is_u = (w < 128);
  const int wl = is_u ? w : (w - 128);
  const int mt = wl & 3, nt = wl >> 2;                 // mt 0..3, nt 0..31
  const int col = nt * 16 + cl;                        // 0..511
  const int wcol1 = is_u ? (512 + col) : col;          // row of W_ruh_T

  // register-resident weight fragments (reused all 32 steps)
  bf16x8s bw1[16];
  { const bf16* bp = W_ruh_T + (size_t)wcol1 * NH + g * 8;
#pragma unroll
    for (int k = 0; k < 16; k++) bw1[k] = *(const bf16x8s*)(bp + k * 32); }
  bf16x8s bw2[16];
  float h_reg[4];
  if (is_u) {
    const bf16* bp = W_hh_T + (size_t)col * NH + g * 8;
#pragma unroll
    for (int k = 0; k < 16; k++) bw2[k] = *(const bf16x8s*)(bp + k * 32);
#pragma unroll
    for (int j = 0; j < 4; j++)
      h_reg[j] = h0f[(size_t)(mt * 16 + g * 4 + j) * NH + col];
  }

  const bf16* hrow  = hb   + (size_t)(mt * 16 + cl) * NH + g * 8;
  const bf16* rhrow = rh_b + (size_t)(mt * 16 + cl) * NH + g * 8;
  float u_reg[4];

  for (int t = 0; t < NS; t++) {
    { // ---- phase 1: u-gate (is_u, regs) / r-gate -> rh store (!is_u)
      i32x4 fr[16];
#pragma unroll
      for (int k = 0; k < 16; k++) fr[k] = ld16_sc(hrow + k * 32);
      unsigned hv[4];
      if (!is_u) {
#pragma unroll
        for (int j = 0; j < 4; j++)
          hv[j] = ldus_sc(hb + (size_t)(mt * 16 + g * 4 + j) * NH + col);
      }
      wait_vm0();
      f32x4 acc0 = {0.f,0.f,0.f,0.f}, acc1 = {0.f,0.f,0.f,0.f};
#pragma unroll
      for (int k = 0; k < 16; k += 2) {
        acc0 = mfma16(*(bf16x8s*)&fr[k],     bw1[k],     acc0);
        acc1 = mfma16(*(bf16x8s*)&fr[k + 1], bw1[k + 1], acc1);
      }
#pragma unroll
      for (int j = 0; j < 4; j++) {
        int b = mt * 16 + g * 4 + j;
        float pv = pre[(size_t)(b * NS + t) * 1536 + wcol1];
        float gate = 1.f / (1.f + expf(-(acc0[j] + acc1[j] + pv)));
        if (is_u) {
          u_reg[j] = gate;
        } else {
          unsigned short us = (unsigned short)hv[j];
          bf16 hbv = *(bf16*)&us;
          bf16 o = f2bf(gate * bf2f(hbv));
          stus_sc(rh_b + (size_t)b * NH + col, *(unsigned short*)&o);
        }
      }
    }
    gbar(barcnt, 2 * t + 1);
    if (is_u) { // ---- phase 2: h_tilde + combine (u, h in registers)
      i32x4 fr[16];
#pragma unroll
      for (int k = 0; k < 16; k++) fr[k] = ld16_sc(rhrow + k * 32);
      wait_vm0();
      f32x4 acc0 = {0.f,0.f,0.f,0.f}, acc1 = {0.f,0.f,0.f,0.f};
#pragma unroll
      for (int k = 0; k < 16; k += 2) {
        acc0 = mfma16(*(bf16x8s*)&fr[k],     bw2[k],     acc0);
        acc1 = mfma16(*(bf16x8s*)&fr[k + 1], bw2[k + 1], acc1);
      }
#pragma unroll
      for (int j = 0; j < 4; j++) {
        int b = mt * 16 + g * 4 + j;
        float pv = pre[(size_t)(b * NS + t) * 1536 + 1024 + col];
        float htil = tanhf(acc0[j] + acc1[j] + pv);
        float hnew = h_reg[j] * u_reg[j] + (1.f - u_reg[j]) * htil;
        h_reg[j] = hnew;
        bf16 hn = f2bf(hnew);
        stus_sc(hb + (size_t)b * NH + col, *(unsigned short*)&hn);
        seq[(size_t)(b * NS + t) * NH + col] = hn;   // cached: consumed next kernel
      }
    }
    if (t + 1 < NS) gbar(barcnt, 2 * t + 2);
  }
}

// ---------------- logits = seq1 @ w_out + b_out ----------------
__global__ void k_gemm_out(const bf16* __restrict__ A, const bf16* __restrict__ BT,
                           const float* __restrict__ bias, float* __restrict__ out) {
  int wid = blockIdx.x * 4 + (threadIdx.x >> 6);
  int mg = wid % 32, ng = wid / 32;
  int lane = threadIdx.x & 63;
  int cl = lane & 15, g = lane >> 4;
  f32x4 acc[4][4] = {};
  const bf16* a0 = A + (size_t)(mg * 64 + cl) * NE + g * 8;
  const bf16* b0 = BT + (size_t)(ng * 64 + cl) * NE + g * 8;
#pragma unroll 2
  for (int k = 0; k < NE; k += 32) {
    bf16x8s av[4], bv[4];
#pragma unroll
    for (int i = 0; i < 4; i++) av[i] = *(const bf16x8s*)(a0 + (size_t)(i * 16) * NE + k);
#pragma unroll
    for (int i = 0; i < 4; i++) bv[i] = *(const bf16x8s*)(b0 + (size_t)(i * 16) * NE + k);
#pragma unroll
    for (int mi = 0; mi < 4; mi++)
#pragma unroll
      for (int ni = 0; ni < 4; ni++)
        acc[mi][ni] = mfma16(av[mi], bv[ni], acc[mi][ni]);
  }
#pragma unroll
  for (int mi = 0; mi < 4; mi++) {
#pragma unroll
    for (int ni = 0; ni < 4; ni++) {
      int colb = ng * 64 + ni * 16 + cl;
      if (colb < NV) {
        float bv2 = bias[colb];
#pragma unroll
        for (int j = 0; j < 4; j++) {
          int row = mg * 64 + mi * 16 + g * 4 + j;
          out[(size_t)row * NV + colb] = acc[mi][ni][j] + bv2;
        }
      }
    }
  }
}

extern "C" void kernel_launch(void* const* d_in, const int* in_sizes, int n_in,
                              void* d_out, int out_size, void* d_ws, size_t ws_size,
                              hipStream_t stream) {
  const int*   tokens = (const int*)d_in[0];
  const float* cnn    = (const float*)d_in[1];
  const float* emb    = (const float*)d_in[2];
  const float* w_in   = (const float*)d_in[3];
  const float* b_in   = (const float*)d_in[4];
  const float* w_r    = (const float*)d_in[5];
  const float* b_r    = (const float*)d_in[6];
  const float* w_u    = (const float*)d_in[7];
  const float* b_u    = (const float*)d_in[8];
  const float* w_h    = (const float*)d_in[9];
  const float* b_h    = (const float*)d_in[10];
  const float* w_out  = (const float*)d_in[11];
  const float* b_out  = (const float*)d_in[12];
  float* out = (float*)d_out;

  char* ws = (char*)d_ws;
  size_t off = 0;
  auto alloc = [&](size_t bytes) { char* p = ws + off; off += (bytes + 255) & ~(size_t)255; return p; };
  bf16*  x0      = (bf16*) alloc((size_t)2048 * 512 * 2);
  bf16*  seq0    = (bf16*) alloc((size_t)2048 * 512 * 2);
  bf16*  seq1    = (bf16*) alloc((size_t)2048 * 512 * 2);
  float* pre     = (float*)alloc((size_t)2048 * 1536 * 4);
  float* h0f     = (float*)alloc((size_t)64 * 512 * 4);
  bf16*  h0b     = (bf16*) alloc((size_t)64 * 512 * 2);
  bf16*  hb      = (bf16*) alloc((size_t)64 * 512 * 2);
  bf16*  rh_b    = (bf16*) alloc((size_t)64 * 512 * 2);
  float* bias3   = (float*)alloc((size_t)2 * 1536 * 4);
  bf16*  cnn_b   = (bf16*) alloc((size_t)64 * 2048 * 2);
  bf16*  w_in_T  = (bf16*) alloc((size_t)512 * 2048 * 2);
  bf16*  w_ruh_T = (bf16*) alloc((size_t)2 * 1024 * 512 * 2);
  bf16*  w_hh_T  = (bf16*) alloc((size_t)2 * 512 * 512 * 2);
  bf16*  w_x_T   = (bf16*) alloc((size_t)2 * 1536 * 512 * 2);
  bf16*  w_out_T = (bf16*) alloc((size_t)10048 * 512 * 2);
  unsigned* barcnt = (unsigned*)alloc(256);
  (void)ws_size; (void)in_sizes; (void)n_in; (void)out_size;

  hipMemsetAsync(barcnt, 0, 256, stream);
  hipMemsetAsync(w_out_T + (size_t)10000 * 512, 0, (size_t)48 * 512 * 2, stream);

  k_embed<<<2048, 256, 0, stream>>>(tokens, emb, x0);
  k_cvt<<<512, 256, 0, stream>>>(cnn, cnn_b, 64 * 2048);
  k_transpose<<<dim3(16, 64), 256, 0, stream>>>(w_in, w_in_T, NF, NH);
  k_transpose12<<<dim3(16, 16, 12), 256, 0, stream>>>(w_r, w_u, w_h, w_ruh_T, w_hh_T, w_x_T);
  k_transpose<<<dim3(313, 16), 256, 0, stream>>>(w_out, w_out_T, 512, NV);
  k_bias3all<<<12, 256, 0, stream>>>(b_r, b_u, b_h, bias3);

  k_gemm_h0<<<32, 256, 0, stream>>>(cnn_b, w_in_T, b_in, h0f, h0b);

  const bf16* seq_in[2] = {x0, seq0};
  bf16* seq_out[2] = {seq0, seq1};
  for (int l = 0; l < 2; l++) {
    k_gemm_pre<<<3072, 256, 0, stream>>>(seq_in[l], w_x_T + (size_t)l * 1536 * 512,
                                         bias3 + (size_t)l * 1536, pre);
    hipMemcpyAsync(hb, h0b, (size_t)64 * 512 * 2, hipMemcpyDeviceToDevice, stream);
    k_gru_layer<<<G_WGS, 512, 0, stream>>>(w_ruh_T + (size_t)l * 1024 * 512,
                                           w_hh_T + (size_t)l * 512 * 512,
                                           pre, h0f, hb, rh_b, seq_out[l], barcnt + l);
  }

  k_gemm_out<<<1256, 256, 0, stream>>>(seq1, w_out_T, b_out, out);
}

// Round 6
// 589.909 us; speedup vs baseline: 7.4376x; 2.6535x over previous
//
#include <hip/hip_runtime.h>
#include <hip/hip_bf16.h>

typedef __hip_bfloat16 bf16;
typedef __attribute__((ext_vector_type(8))) short bf16x8s;
typedef __attribute__((ext_vector_type(4))) float f32x4;
typedef __attribute__((ext_vector_type(4))) int i32x4;

#define NB 64
#define NS 32
#define NV 10000
#define NE 512
#define NH 512
#define NF 2048
#define ND 1024

static __device__ __forceinline__ float bf2f(bf16 x) { return __bfloat162float(x); }
static __device__ __forceinline__ bf16 f2bf(float x) { return __float2bfloat16(x); }
static __device__ __forceinline__ f32x4 mfma16(bf16x8s a, bf16x8s b, f32x4 c) {
  return __builtin_amdgcn_mfma_f32_16x16x32_bf16(a, b, c, 0, 0, 0);
}

// ---- LLC-coherent (cross-XCD) accesses: bypass per-XCD L1/L2 via sc0 sc1.
// Compiler does NOT track vmcnt for these — explicit s_waitcnt before use.
static __device__ __forceinline__ i32x4 ld16_sc(const void* p) {
  i32x4 r;
  asm volatile("global_load_dwordx4 %0, %1, off sc0 sc1" : "=v"(r) : "v"(p) : "memory");
  return r;
}
static __device__ __forceinline__ void stus_sc(void* p, unsigned v) {
  asm volatile("global_store_short %0, %1, off sc0 sc1" :: "v"(p), "v"(v) : "memory");
}

// One 16x16 output tile per wave (cached path, for the plain GEMMs).
__device__ __forceinline__ f32x4 wave_tile16(const bf16* A, const bf16* BT,
                                             int lda, int K, int m0, int n0) {
  int lane = threadIdx.x & 63;
  int r = lane & 15, g = lane >> 4;
  const bf16* ap = A + (size_t)(m0 + r) * lda + g * 8;
  const bf16* bp = BT + (size_t)(n0 + r) * K + g * 8;
  f32x4 acc = {0.f, 0.f, 0.f, 0.f};
#pragma unroll 4
  for (int k = 0; k < K; k += 32) {
    bf16x8s a = *(const bf16x8s*)(ap + k);
    bf16x8s b = *(const bf16x8s*)(bp + k);
    acc = mfma16(a, b, acc);
  }
  return acc;
}

// ---------------- embedding gather + f32->bf16 ----------------
__global__ void k_embed(const int* __restrict__ tokens, const float* __restrict__ emb,
                        bf16* __restrict__ x0) {
  int row = blockIdx.x;
  int tok = tokens[row];
  const float2* src = (const float2*)(emb + (size_t)tok * NE);
  uint32_t* dst = (uint32_t*)(x0 + (size_t)row * NE);
  float2 v = src[threadIdx.x];
  __hip_bfloat162 p;
  p.x = f2bf(v.x); p.y = f2bf(v.y);
  dst[threadIdx.x] = *(uint32_t*)&p;
}

__global__ void k_cvt(const float* __restrict__ src, bf16* __restrict__ dst, int n) {
  int i = blockIdx.x * 256 + threadIdx.x;
  if (i < n) dst[i] = f2bf(src[i]);
}

__global__ void k_transpose(const float* __restrict__ src, bf16* __restrict__ dst,
                            int K, int N) {
  __shared__ float tile[32][33];
  int n0 = blockIdx.x * 32, k0 = blockIdx.y * 32;
  int tx = threadIdx.x & 31, ty = threadIdx.x >> 5;
  for (int i = ty; i < 32; i += 8) {
    int k = k0 + i, n = n0 + tx;
    tile[i][tx] = (k < K && n < N) ? src[(size_t)k * N + n] : 0.f;
  }
  __syncthreads();
  for (int i = ty; i < 32; i += 8) {
    int n = n0 + i, k = k0 + tx;
    if (n < N && k < K) dst[(size_t)n * K + k] = f2bf(tile[tx][i]);
  }
}

__global__ void k_transpose12(const float* __restrict__ w_r, const float* __restrict__ w_u,
                              const float* __restrict__ w_h, bf16* __restrict__ ruhT,
                              bf16* __restrict__ hhT, bf16* __restrict__ xT) {
  int z = blockIdx.z, l = z / 6, q = z % 6;
  const float* srcs[6] = {
    w_r + (size_t)l * ND * NH + (size_t)512 * NH,
    w_u + (size_t)l * ND * NH + (size_t)512 * NH,
    w_h + (size_t)l * ND * NH + (size_t)512 * NH,
    w_r + (size_t)l * ND * NH,
    w_u + (size_t)l * ND * NH,
    w_h + (size_t)l * ND * NH };
  bf16* dsts[6] = {
    ruhT + (size_t)l * 1024 * 512,
    ruhT + (size_t)l * 1024 * 512 + 512 * 512,
    hhT  + (size_t)l * 512 * 512,
    xT   + (size_t)l * 1536 * 512,
    xT   + (size_t)l * 1536 * 512 + 512 * 512,
    xT   + (size_t)l * 1536 * 512 + 1024 * 512 };
  const float* src = srcs[q];
  bf16* dst = dsts[q];
  __shared__ float tile[32][33];
  int n0 = blockIdx.x * 32, k0 = blockIdx.y * 32;
  int tx = threadIdx.x & 31, ty = threadIdx.x >> 5;
  for (int i = ty; i < 32; i += 8)
    tile[i][tx] = src[(size_t)(k0 + i) * NH + n0 + tx];
  __syncthreads();
  for (int i = ty; i < 32; i += 8)
    dst[(size_t)(n0 + i) * NH + k0 + tx] = f2bf(tile[tx][i]);
}

__global__ void k_bias3all(const float* __restrict__ br, const float* __restrict__ bu,
                           const float* __restrict__ bh, float* __restrict__ bias) {
  int i = blockIdx.x * 256 + threadIdx.x;
  if (i < 3072) {
    int l = i / 1536, c = i % 1536;
    const float* s = (c < 512) ? (br + l * 512 + c)
                   : (c < 1024 ? (bu + l * 512 + (c - 512)) : (bh + l * 512 + (c - 1024)));
    bias[i] = *s;
  }
}

// ---------------- h0 = cnn @ w_in + b_in, dual-store f32 + bf16 ----------------
__global__ void k_gemm_h0(const bf16* __restrict__ A, const bf16* __restrict__ BT,
                          const float* __restrict__ bias,
                          float* __restrict__ h0f, bf16* __restrict__ h0b) {
  int wid = blockIdx.x * 4 + (threadIdx.x >> 6);
  int mt = wid & 3, nt = wid >> 2;
  f32x4 acc = wave_tile16(A, BT, NF, NF, mt * 16, nt * 16);
  int lane = threadIdx.x & 63;
  int cl = lane & 15, g = lane >> 4;
  int col = nt * 16 + cl;
  float bv = bias[col];
#pragma unroll
  for (int j = 0; j < 4; j++) {
    int row = mt * 16 + g * 4 + j;
    float v = acc[j] + bv;
    h0f[(size_t)row * NH + col] = v;
    h0b[(size_t)row * NH + col] = f2bf(v);
  }
}

__global__ void k_gemm_pre(const bf16* __restrict__ A, const bf16* __restrict__ BT,
                           const float* __restrict__ bias, float* __restrict__ pre) {
  int wid = (blockIdx.x * blockDim.x + threadIdx.x) >> 6;
  int mt = wid % 128, nt = wid / 128;
  f32x4 acc = wave_tile16(A, BT, NE, NE, mt * 16, nt * 16);
  int lane = threadIdx.x & 63;
  int cl = lane & 15, g = lane >> 4;
  int col = nt * 16 + cl;
  float bv = bias[col];
#pragma unroll
  for (int j = 0; j < 4; j++) {
    int row = mt * 16 + g * 4 + j;
    pre[(size_t)row * 1536 + col] = acc[j] + bv;
  }
}

// ---------------- persistent GRU layer, batch-group factorized ----------------
// 32 WGs x 512 thr. Group = mt = wg&3 owns batches mt*16..mt*16+15; groups are
// fully independent (separate barrier counters). Within a WG: waves 0..3 = r/h
// waves (W_r,W_h register-resident; own h f32 in regs), waves 4..7 = u waves
// (W_u resident; u handed over via LDS). Cross-WG state (h, rh slabs, 16KB each)
// moves via sc0sc1 ops + per-group counter barrier; A-fragments come from
// XOR-swizzled LDS panels (conflict-free ds_read_b128).
__global__ __launch_bounds__(512, 2)
void k_gru_layer(const bf16* __restrict__ W_ruh_T, const bf16* __restrict__ W_hh_T,
                 const float* __restrict__ pre, const float* __restrict__ h0f,
                 const bf16* __restrict__ h0b, bf16* __restrict__ hb,
                 bf16* __restrict__ rh_g, bf16* __restrict__ seq,
                 unsigned* __restrict__ barcnt) {
  __shared__ i32x4 lds_raw[36864 / 16];
  char* hp = (char*)lds_raw;            // h panel, swizzled [16][512] bf16
  char* rp = (char*)lds_raw + 16384;    // rh panel, swizzled
  float* ul = (float*)((char*)lds_raw + 32768);  // u exchange [16][64] f32

  const int tid = threadIdx.x;
  const int lane = tid & 63;
  const int wv = tid >> 6;              // 0..7
  const int cl = lane & 15, g = lane >> 4;
  const int wg = blockIdx.x;            // 0..31
  const int mt = wg & 3, ng = wg >> 2;  // group, ng 0..7
  const bool is_u = (wv >= 4);
  const int wsub = wv & 3;
  const int nt = ng * 4 + wsub;         // 0..31
  const int c = nt * 16 + cl;           // output col 0..511
  unsigned* cnt = barcnt + mt * 16;     // per-group counter, 64B apart

  // register-resident weights (reused all 32 steps)
  bf16x8s bwA[16];                      // r/h-wave: W_r rows c ; u-wave: W_u rows 512+c
  { const bf16* pa = W_ruh_T + (size_t)(is_u ? 512 + c : c) * NH + g * 8;
#pragma unroll
    for (int k = 0; k < 16; k++) bwA[k] = *(const bf16x8s*)(pa + k * 32); }
  bf16x8s bwB[16];                      // r/h-wave: W_h rows c
  float h_reg[4];
  if (!is_u) {
    const bf16* pb = W_hh_T + (size_t)c * NH + g * 8;
#pragma unroll
    for (int k = 0; k < 16; k++) bwB[k] = *(const bf16x8s*)(pb + k * 32);
#pragma unroll
    for (int j = 0; j < 4; j++)
      h_reg[j] = h0f[(size_t)(mt * 16 + g * 4 + j) * NH + c];
  }

  const size_t slab = (size_t)mt * 16 * NH;   // byte offset /2 (bf16 elems)
  const char* h0_slab = (const char*)(h0b + slab);
  const char* hb_slab = (const char*)(hb + slab);
  const char* rh_slab = (const char*)(rh_g + slab);

  // stage 16KB slab -> swizzled LDS panel (2 x 16B per thread)
  auto stage = [&](char* dst, const char* src) {
    int o0 = tid * 32, o1 = o0 + 16;
    i32x4 v0 = ld16_sc(src + o0);
    i32x4 v1 = ld16_sc(src + o1);
    asm volatile("s_waitcnt vmcnt(0)" ::: "memory");
    __builtin_amdgcn_sched_barrier(0);
    *(i32x4*)(dst + ((o0 & ~1023) | ((o0 & 1023) ^ (((o0 >> 10) & 7) << 4)))) = v0;
    *(i32x4*)(dst + ((o1 & ~1023) | ((o1 & 1023) ^ (((o1 >> 10) & 7) << 4)))) = v1;
  };
  // A-fragment from swizzled panel: row=cl, k-bytes = g*16 + kk*64
  auto afrag = [&](const char* panel, int kk) {
    return *(const bf16x8s*)(panel + cl * 1024 + ((g * 16 + kk * 64) ^ ((cl & 7) << 4)));
  };
  // per-group barrier: drain sc ops, arrive, poll (no cache maintenance needed)
  auto gbar = [&](unsigned target) {
    asm volatile("s_waitcnt vmcnt(0)" ::: "memory");
    __syncthreads();
    if (tid == 0) {
      atomicAdd(cnt, 1u);
      while (__hip_atomic_load(cnt, __ATOMIC_RELAXED, __HIP_MEMORY_SCOPE_AGENT) < 8u * target)
        __builtin_amdgcn_s_sleep(1);
    }
    __syncthreads();
    __builtin_amdgcn_sched_barrier(0);
  };

  stage(hp, h0_slab);
  __syncthreads();
  unsigned ep = 0;

  for (int t = 0; t < NS; t++) {
    // pre values for this step (cached loads, overlap with LDS reads + MFMA)
    float pA[4], pB[4];
    const int colA = is_u ? 512 + c : c;
#pragma unroll
    for (int j = 0; j < 4; j++) {
      int b = mt * 16 + g * 4 + j;
      pA[j] = pre[(size_t)(b * NS + t) * 1536 + colA];
      if (!is_u) pB[j] = pre[(size_t)(b * NS + t) * 1536 + 1024 + c];
    }
    // ---- phase 1: r-gate (r/h-waves) / u-gate (u-waves), A = h panel
    f32x4 acc = {0.f, 0.f, 0.f, 0.f};
#pragma unroll
    for (int k4 = 0; k4 < 4; k4++) {
      bf16x8s a0 = afrag(hp, k4 * 4 + 0), a1 = afrag(hp, k4 * 4 + 1);
      bf16x8s a2 = afrag(hp, k4 * 4 + 2), a3 = afrag(hp, k4 * 4 + 3);
      acc = mfma16(a0, bwA[k4 * 4 + 0], acc);
      acc = mfma16(a1, bwA[k4 * 4 + 1], acc);
      acc = mfma16(a2, bwA[k4 * 4 + 2], acc);
      acc = mfma16(a3, bwA[k4 * 4 + 3], acc);
    }
#pragma unroll
    for (int j = 0; j < 4; j++) {
      float gate = 1.f / (1.f + expf(-(acc[j] + pA[j])));
      if (is_u) {
        ul[(g * 4 + j) * 64 + wsub * 16 + cl] = gate;   // hand u to paired r/h wave
      } else {
        int b = mt * 16 + g * 4 + j;
        bf16 o = f2bf(gate * h_reg[j]);
        stus_sc((void*)(rh_g + (size_t)b * NH + c), *(unsigned short*)&o);
      }
    }
    gbar(++ep);
    stage(rp, rh_slab);
    __syncthreads();
    // ---- phase 2: h_tilde + combine (r/h-waves only)
    if (!is_u) {
      f32x4 acc2 = {0.f, 0.f, 0.f, 0.f};
#pragma unroll
      for (int k4 = 0; k4 < 4; k4++) {
        bf16x8s a0 = afrag(rp, k4 * 4 + 0), a1 = afrag(rp, k4 * 4 + 1);
        bf16x8s a2 = afrag(rp, k4 * 4 + 2), a3 = afrag(rp, k4 * 4 + 3);
        acc2 = mfma16(a0, bwB[k4 * 4 + 0], acc2);
        acc2 = mfma16(a1, bwB[k4 * 4 + 1], acc2);
        acc2 = mfma16(a2, bwB[k4 * 4 + 2], acc2);
        acc2 = mfma16(a3, bwB[k4 * 4 + 3], acc2);
      }
#pragma unroll
      for (int j = 0; j < 4; j++) {
        int b = mt * 16 + g * 4 + j;
        float u = ul[(g * 4 + j) * 64 + wsub * 16 + cl];
        float htil = tanhf(acc2[j] + pB[j]);
        float hnew = h_reg[j] * u + (1.f - u) * htil;
        h_reg[j] = hnew;
        bf16 hn = f2bf(hnew);
        stus_sc((void*)(hb + (size_t)b * NH + c), *(unsigned short*)&hn);
        seq[(size_t)(b * NS + t) * NH + c] = hn;    // cached, consumed next kernel
      }
    }
    if (t + 1 < NS) {
      gbar(++ep);
      stage(hp, hb_slab);
      __syncthreads();
    }
  }
}

// ---------------- logits = seq1 @ w_out + b_out ----------------
__global__ void k_gemm_out(const bf16* __restrict__ A, const bf16* __restrict__ BT,
                           const float* __restrict__ bias, float* __restrict__ out) {
  int wid = blockIdx.x * 4 + (threadIdx.x >> 6);
  int mg = wid % 32, ng = wid / 32;
  int lane = threadIdx.x & 63;
  int cl = lane & 15, g = lane >> 4;
  f32x4 acc[4][4] = {};
  const bf16* a0 = A + (size_t)(mg * 64 + cl) * NE + g * 8;
  const bf16* b0 = BT + (size_t)(ng * 64 + cl) * NE + g * 8;
#pragma unroll 2
  for (int k = 0; k < NE; k += 32) {
    bf16x8s av[4], bv[4];
#pragma unroll
    for (int i = 0; i < 4; i++) av[i] = *(const bf16x8s*)(a0 + (size_t)(i * 16) * NE + k);
#pragma unroll
    for (int i = 0; i < 4; i++) bv[i] = *(const bf16x8s*)(b0 + (size_t)(i * 16) * NE + k);
#pragma unroll
    for (int mi = 0; mi < 4; mi++)
#pragma unroll
      for (int ni = 0; ni < 4; ni++)
        acc[mi][ni] = mfma16(av[mi], bv[ni], acc[mi][ni]);
  }
#pragma unroll
  for (int mi = 0; mi < 4; mi++) {
#pragma unroll
    for (int ni = 0; ni < 4; ni++) {
      int colb = ng * 64 + ni * 16 + cl;
      if (colb < NV) {
        float bv2 = bias[colb];
#pragma unroll
        for (int j = 0; j < 4; j++) {
          int row = mg * 64 + mi * 16 + g * 4 + j;
          out[(size_t)row * NV + colb] = acc[mi][ni][j] + bv2;
        }
      }
    }
  }
}

extern "C" void kernel_launch(void* const* d_in, const int* in_sizes, int n_in,
                              void* d_out, int out_size, void* d_ws, size_t ws_size,
                              hipStream_t stream) {
  const int*   tokens = (const int*)d_in[0];
  const float* cnn    = (const float*)d_in[1];
  const float* emb    = (const float*)d_in[2];
  const float* w_in   = (const float*)d_in[3];
  const float* b_in   = (const float*)d_in[4];
  const float* w_r    = (const float*)d_in[5];
  const float* b_r    = (const float*)d_in[6];
  const float* w_u    = (const float*)d_in[7];
  const float* b_u    = (const float*)d_in[8];
  const float* w_h    = (const float*)d_in[9];
  const float* b_h    = (const float*)d_in[10];
  const float* w_out  = (const float*)d_in[11];
  const float* b_out  = (const float*)d_in[12];
  float* out = (float*)d_out;

  char* ws = (char*)d_ws;
  size_t off = 0;
  auto alloc = [&](size_t bytes) { char* p = ws + off; off += (bytes + 255) & ~(size_t)255; return p; };
  bf16*  x0      = (bf16*) alloc((size_t)2048 * 512 * 2);
  bf16*  seq0    = (bf16*) alloc((size_t)2048 * 512 * 2);
  bf16*  seq1    = (bf16*) alloc((size_t)2048 * 512 * 2);
  float* pre     = (float*)alloc((size_t)2048 * 1536 * 4);
  float* h0f     = (float*)alloc((size_t)64 * 512 * 4);
  bf16*  h0b     = (bf16*) alloc((size_t)64 * 512 * 2);
  bf16*  hb      = (bf16*) alloc((size_t)64 * 512 * 2);
  bf16*  rh_g    = (bf16*) alloc((size_t)64 * 512 * 2);
  float* bias3   = (float*)alloc((size_t)2 * 1536 * 4);
  bf16*  cnn_b   = (bf16*) alloc((size_t)64 * 2048 * 2);
  bf16*  w_in_T  = (bf16*) alloc((size_t)512 * 2048 * 2);
  bf16*  w_ruh_T = (bf16*) alloc((size_t)2 * 1024 * 512 * 2);
  bf16*  w_hh_T  = (bf16*) alloc((size_t)2 * 512 * 512 * 2);
  bf16*  w_x_T   = (bf16*) alloc((size_t)2 * 1536 * 512 * 2);
  bf16*  w_out_T = (bf16*) alloc((size_t)10048 * 512 * 2);
  unsigned* barcnt = (unsigned*)alloc(512);   // 2 layers x 4 groups x 64B
  (void)ws_size; (void)in_sizes; (void)n_in; (void)out_size;

  hipMemsetAsync(barcnt, 0, 512, stream);
  hipMemsetAsync(w_out_T + (size_t)10000 * 512, 0, (size_t)48 * 512 * 2, stream);

  k_embed<<<2048, 256, 0, stream>>>(tokens, emb, x0);
  k_cvt<<<512, 256, 0, stream>>>(cnn, cnn_b, 64 * 2048);
  k_transpose<<<dim3(16, 64), 256, 0, stream>>>(w_in, w_in_T, NF, NH);
  k_transpose12<<<dim3(16, 16, 12), 256, 0, stream>>>(w_r, w_u, w_h, w_ruh_T, w_hh_T, w_x_T);
  k_transpose<<<dim3(313, 16), 256, 0, stream>>>(w_out, w_out_T, 512, NV);
  k_bias3all<<<12, 256, 0, stream>>>(b_r, b_u, b_h, bias3);

  k_gemm_h0<<<32, 256, 0, stream>>>(cnn_b, w_in_T, b_in, h0f, h0b);

  const bf16* seq_in[2] = {x0, seq0};
  bf16* seq_out[2] = {seq0, seq1};
  for (int l = 0; l < 2; l++) {
    k_gemm_pre<<<3072, 256, 0, stream>>>(seq_in[l], w_x_T + (size_t)l * 1536 * 512,
                                         bias3 + (size_t)l * 1536, pre);
    k_gru_layer<<<32, 512, 0, stream>>>(w_ruh_T + (size_t)l * 1024 * 512,
                                        w_hh_T + (size_t)l * 512 * 512,
                                        pre, h0f, h0b, hb, rh_g, seq_out[l],
                                        barcnt + l * 64);
  }

  k_gemm_out<<<1256, 256, 0, stream>>>(seq1, w_out_T, b_out, out);
}

// Round 7
// 465.285 us; speedup vs baseline: 9.4297x; 1.2678x over previous
//
#include <hip/hip_runtime.h>
#include <hip/hip_bf16.h>

typedef __hip_bfloat16 bf16;
typedef __attribute__((ext_vector_type(8))) short bf16x8s;
typedef __attribute__((ext_vector_type(4))) float f32x4;
typedef __attribute__((ext_vector_type(4))) int i32x4;

#define NB 64
#define NS 32
#define NV 10000
#define NE 512
#define NH 512
#define NF 2048
#define ND 1024

static __device__ __forceinline__ float bf2f(bf16 x) { return __bfloat162float(x); }
static __device__ __forceinline__ bf16 f2bf(float x) { return __float2bfloat16(x); }
static __device__ __forceinline__ f32x4 mfma16(bf16x8s a, bf16x8s b, f32x4 c) {
  return __builtin_amdgcn_mfma_f32_16x16x32_bf16(a, b, c, 0, 0, 0);
}

// ---- LLC-coherent (cross-XCD) accesses: bypass per-XCD L1/L2 via sc0 sc1.
// Compiler does NOT track vmcnt for these — explicit s_waitcnt before use.
static __device__ __forceinline__ i32x4 ld16_sc(const void* p) {
  i32x4 r;
  asm volatile("global_load_dwordx4 %0, %1, off sc0 sc1" : "=v"(r) : "v"(p) : "memory");
  return r;
}
static __device__ __forceinline__ void stus_sc(void* p, unsigned v) {
  asm volatile("global_store_short %0, %1, off sc0 sc1" :: "v"(p), "v"(v) : "memory");
}
static __device__ __forceinline__ void stud_sc(void* p, unsigned v) {
  asm volatile("global_store_dword %0, %1, off sc0 sc1" :: "v"(p), "v"(v) : "memory");
}

// One 16x16 output tile per wave (cached path, for the plain GEMMs).
__device__ __forceinline__ f32x4 wave_tile16(const bf16* A, const bf16* BT,
                                             int lda, int K, int m0, int n0) {
  int lane = threadIdx.x & 63;
  int r = lane & 15, g = lane >> 4;
  const bf16* ap = A + (size_t)(m0 + r) * lda + g * 8;
  const bf16* bp = BT + (size_t)(n0 + r) * K + g * 8;
  f32x4 acc = {0.f, 0.f, 0.f, 0.f};
#pragma unroll 4
  for (int k = 0; k < K; k += 32) {
    bf16x8s a = *(const bf16x8s*)(ap + k);
    bf16x8s b = *(const bf16x8s*)(bp + k);
    acc = mfma16(a, b, acc);
  }
  return acc;
}

// ---------------- embedding gather + f32->bf16 ----------------
__global__ void k_embed(const int* __restrict__ tokens, const float* __restrict__ emb,
                        bf16* __restrict__ x0) {
  int row = blockIdx.x;
  int tok = tokens[row];
  const float2* src = (const float2*)(emb + (size_t)tok * NE);
  uint32_t* dst = (uint32_t*)(x0 + (size_t)row * NE);
  float2 v = src[threadIdx.x];
  __hip_bfloat162 p;
  p.x = f2bf(v.x); p.y = f2bf(v.y);
  dst[threadIdx.x] = *(uint32_t*)&p;
}

__global__ void k_cvt(const float* __restrict__ src, bf16* __restrict__ dst, int n) {
  int i = blockIdx.x * 256 + threadIdx.x;
  if (i < n) dst[i] = f2bf(src[i]);
}

__global__ void k_transpose(const float* __restrict__ src, bf16* __restrict__ dst,
                            int K, int N) {
  __shared__ float tile[32][33];
  int n0 = blockIdx.x * 32, k0 = blockIdx.y * 32;
  int tx = threadIdx.x & 31, ty = threadIdx.x >> 5;
  for (int i = ty; i < 32; i += 8) {
    int k = k0 + i, n = n0 + tx;
    tile[i][tx] = (k < K && n < N) ? src[(size_t)k * N + n] : 0.f;
  }
  __syncthreads();
  for (int i = ty; i < 32; i += 8) {
    int n = n0 + i, k = k0 + tx;
    if (n < N && k < K) dst[(size_t)n * K + k] = f2bf(tile[tx][i]);
  }
}

__global__ void k_transpose12(const float* __restrict__ w_r, const float* __restrict__ w_u,
                              const float* __restrict__ w_h, bf16* __restrict__ ruhT,
                              bf16* __restrict__ hhT, bf16* __restrict__ xT) {
  int z = blockIdx.z, l = z / 6, q = z % 6;
  const float* srcs[6] = {
    w_r + (size_t)l * ND * NH + (size_t)512 * NH,
    w_u + (size_t)l * ND * NH + (size_t)512 * NH,
    w_h + (size_t)l * ND * NH + (size_t)512 * NH,
    w_r + (size_t)l * ND * NH,
    w_u + (size_t)l * ND * NH,
    w_h + (size_t)l * ND * NH };
  bf16* dsts[6] = {
    ruhT + (size_t)l * 1024 * 512,
    ruhT + (size_t)l * 1024 * 512 + 512 * 512,
    hhT  + (size_t)l * 512 * 512,
    xT   + (size_t)l * 1536 * 512,
    xT   + (size_t)l * 1536 * 512 + 512 * 512,
    xT   + (size_t)l * 1536 * 512 + 1024 * 512 };
  const float* src = srcs[q];
  bf16* dst = dsts[q];
  __shared__ float tile[32][33];
  int n0 = blockIdx.x * 32, k0 = blockIdx.y * 32;
  int tx = threadIdx.x & 31, ty = threadIdx.x >> 5;
  for (int i = ty; i < 32; i += 8)
    tile[i][tx] = src[(size_t)(k0 + i) * NH + n0 + tx];
  __syncthreads();
  for (int i = ty; i < 32; i += 8)
    dst[(size_t)(n0 + i) * NH + k0 + tx] = f2bf(tile[tx][i]);
}

__global__ void k_bias3all(const float* __restrict__ br, const float* __restrict__ bu,
                           const float* __restrict__ bh, float* __restrict__ bias) {
  int i = blockIdx.x * 256 + threadIdx.x;
  if (i < 3072) {
    int l = i / 1536, c = i % 1536;
    const float* s = (c < 512) ? (br + l * 512 + c)
                   : (c < 1024 ? (bu + l * 512 + (c - 512)) : (bh + l * 512 + (c - 1024)));
    bias[i] = *s;
  }
}

// ---------------- h0 = cnn @ w_in + b_in, dual-store f32 + bf16 ----------------
__global__ void k_gemm_h0(const bf16* __restrict__ A, const bf16* __restrict__ BT,
                          const float* __restrict__ bias,
                          float* __restrict__ h0f, bf16* __restrict__ h0b) {
  int wid = blockIdx.x * 4 + (threadIdx.x >> 6);
  int mt = wid & 3, nt = wid >> 2;
  f32x4 acc = wave_tile16(A, BT, NF, NF, mt * 16, nt * 16);
  int lane = threadIdx.x & 63;
  int cl = lane & 15, g = lane >> 4;
  int col = nt * 16 + cl;
  float bv = bias[col];
#pragma unroll
  for (int j = 0; j < 4; j++) {
    int row = mt * 16 + g * 4 + j;
    float v = acc[j] + bv;
    h0f[(size_t)row * NH + col] = v;
    h0b[(size_t)row * NH + col] = f2bf(v);
  }
}

// ---------------- fused 2-layer persistent GRU ----------------
// 64 WGs x 512 thr: layer = blockIdx>>5, group mt = blockIdx&3 owns batches
// mt*16..+15, ng = (blockIdx&31)>>2 in 0..7 (8 WGs per layer-group).
// x-part GEMM folded in (W_x from L2 each step). Layer l's h output is sc-stored
// into seq_l[:,t] (full per-step buffering); layer1 stages its x-slab from seq0
// gated on layer0's per-WG monotonic h-flags. Per-group flag vectors (8 words,
// polled with 2x dwordx4) replace the atomic counter. Cross-WG data moves ONLY
// via sc0sc1 (LLC-coherent) ops — no cache maintenance anywhere.
__global__ __launch_bounds__(512, 2)
void k_gru_fused(const bf16* __restrict__ W_ruh_T_all, const bf16* __restrict__ W_hh_T_all,
                 const bf16* __restrict__ W_x_T_all, const float* __restrict__ bias3,
                 const float* __restrict__ h0f, const bf16* __restrict__ h0b,
                 const bf16* __restrict__ x0, bf16* __restrict__ seq0,
                 bf16* __restrict__ seq1, bf16* __restrict__ rh_all,
                 unsigned* __restrict__ flags) {
  __shared__ i32x4 lds_raw[53248 / 16];
  char* hp = (char*)lds_raw;                       // h panel  [16][512] bf16, swizzled
  char* rp = (char*)lds_raw + 16384;               // rh panel
  char* xp = (char*)lds_raw + 32768;               // x panel
  float* ul = (float*)((char*)lds_raw + 49152);    // u exchange [16][64] f32

  const int tid = threadIdx.x;
  const int lane = tid & 63;
  const int wv = tid >> 6;
  const int cl = lane & 15, g = lane >> 4;
  const int l = blockIdx.x >> 5;
  const int wg5 = blockIdx.x & 31;
  const int mt = wg5 & 3, ng = wg5 >> 2;
  const bool is_u = (wv >= 4);
  const int wsub = wv & 3;
  const int nt = ng * 4 + wsub;                    // 0..31
  const int c = nt * 16 + cl;                      // 0..511
  const int colA = is_u ? 512 + c : c;

  // flags: [layer][group][which][8(+pad to 32)]
  unsigned* f_rh = flags + l * 256 + mt * 64;
  unsigned* f_h  = f_rh + 32;
  unsigned* f_h0 = flags + 0 * 256 + mt * 64 + 32; // layer0 h flags (x gating)

  const bf16* Wr = W_ruh_T_all + (size_t)l * 1024 * 512;
  const bf16* Wh = W_hh_T_all + (size_t)l * 512 * 512;
  const bf16* Wx = W_x_T_all + (size_t)l * 1536 * 512;
  const bf16* xsrc = l ? seq0 : x0;
  bf16* seql = l ? seq1 : seq0;
  bf16* rh = rh_all + (size_t)l * 64 * 512;

  // register-resident recurrent weights (reused all 32 steps)
  bf16x8s bwA[16];
  { const bf16* pa = Wr + (size_t)colA * NH + g * 8;
#pragma unroll
    for (int k = 0; k < 16; k++) bwA[k] = *(const bf16x8s*)(pa + k * 32); }
  bf16x8s bwB[16];
  float h_reg[4];
  if (!is_u) {
    const bf16* pb = Wh + (size_t)c * NH + g * 8;
#pragma unroll
    for (int k = 0; k < 16; k++) bwB[k] = *(const bf16x8s*)(pb + k * 32);
#pragma unroll
    for (int j = 0; j < 4; j++)
      h_reg[j] = h0f[(size_t)(mt * 16 + g * 4 + j) * NH + c];
  }
  // x-part weight rows (cached loads each step, L2-hot)
  const bf16* wxA = Wx + (size_t)colA * NH + g * 8;
  const bf16* wxB = Wx + (size_t)(1024 + c) * NH + g * 8;
  const float bA = bias3[l * 1536 + colA];
  const float bB = bias3[l * 1536 + 1024 + c];

  // stage 16 rows x 1KB (strided) -> swizzled LDS panel; 2 x 16B per thread
  auto stage = [&](char* dst, const char* srcbase, int rstride) {
    int row = tid >> 5, inner = (tid & 31) * 32;
    const char* s = srcbase + (size_t)row * rstride + inner;
    i32x4 v0 = ld16_sc(s);
    i32x4 v1 = ld16_sc(s + 16);
    asm volatile("s_waitcnt vmcnt(0)" ::: "memory");
    __builtin_amdgcn_sched_barrier(0);
    int sw = (row & 7) << 4;
    *(i32x4*)(dst + ((row * 1024 + inner) ^ sw)) = v0;
    *(i32x4*)(dst + ((row * 1024 + inner + 16) ^ sw)) = v1;
  };
  auto afrag = [&](const char* panel, int kk) {
    return *(const bf16x8s*)(panel + cl * 1024 + ((g * 16 + kk * 64) ^ ((cl & 7) << 4)));
  };
  auto poll8 = [&](const unsigned* f, unsigned tgt) {
    if (tid == 0) {
      for (;;) {
        i32x4 a = ld16_sc(f);
        i32x4 b = ld16_sc(f + 4);
        asm volatile("s_waitcnt vmcnt(0)" ::: "memory");
        unsigned m = min(min(min((unsigned)a[0], (unsigned)a[1]),
                             min((unsigned)a[2], (unsigned)a[3])),
                         min(min((unsigned)b[0], (unsigned)b[1]),
                             min((unsigned)b[2], (unsigned)b[3])));
        if (m >= tgt) break;
        __builtin_amdgcn_s_sleep(2);
      }
    }
    __syncthreads();
    __builtin_amdgcn_sched_barrier(0);
  };
  auto publish = [&](unsigned* f, unsigned val) {
    asm volatile("s_waitcnt vmcnt(0)" ::: "memory");  // per-wave sc-store drain
    __syncthreads();
    if (tid == 0) stud_sc(f + ng, val);
  };

  for (int t = 0; t < NS; t++) {
    // ---- gate + stage phase-1 inputs
    if (t > 0) poll8(f_h, (unsigned)t);              // own h(t-1) complete
    if (l == 1) poll8(f_h0, (unsigned)(t + 1));      // x(t) = layer0 h(t)
    if (t == 0) stage(hp, (const char*)(h0b + (size_t)mt * 16 * NH), 1024);
    else        stage(hp, (const char*)seql + ((size_t)(mt * 16) * NS + (t - 1)) * 1024,
                      NS * 1024);
    stage(xp, (const char*)xsrc + ((size_t)(mt * 16) * NS + t) * 1024, NS * 1024);
    __syncthreads();
    // ---- phase 1: gate = sigmoid(x@Wx + h@W + bias)
    {
      f32x4 acc = {0.f, 0.f, 0.f, 0.f};
#pragma unroll
      for (int k4 = 0; k4 < 4; k4++) {
        bf16x8s w0 = *(const bf16x8s*)(wxA + (k4 * 4 + 0) * 32);
        bf16x8s w1 = *(const bf16x8s*)(wxA + (k4 * 4 + 1) * 32);
        bf16x8s w2 = *(const bf16x8s*)(wxA + (k4 * 4 + 2) * 32);
        bf16x8s w3 = *(const bf16x8s*)(wxA + (k4 * 4 + 3) * 32);
        acc = mfma16(afrag(hp, k4 * 4 + 0), bwA[k4 * 4 + 0], acc);
        acc = mfma16(afrag(hp, k4 * 4 + 1), bwA[k4 * 4 + 1], acc);
        acc = mfma16(afrag(hp, k4 * 4 + 2), bwA[k4 * 4 + 2], acc);
        acc = mfma16(afrag(hp, k4 * 4 + 3), bwA[k4 * 4 + 3], acc);
        acc = mfma16(afrag(xp, k4 * 4 + 0), w0, acc);
        acc = mfma16(afrag(xp, k4 * 4 + 1), w1, acc);
        acc = mfma16(afrag(xp, k4 * 4 + 2), w2, acc);
        acc = mfma16(afrag(xp, k4 * 4 + 3), w3, acc);
      }
#pragma unroll
      for (int j = 0; j < 4; j++) {
        float gate = 1.f / (1.f + expf(-(acc[j] + bA)));
        if (is_u) {
          ul[(g * 4 + j) * 64 + wsub * 16 + cl] = gate;
        } else {
          int b = mt * 16 + g * 4 + j;
          bf16 o = f2bf(gate * h_reg[j]);
          stus_sc((void*)(rh + (size_t)b * NH + c), *(unsigned short*)&o);
        }
      }
    }
    publish(f_rh, (unsigned)(t + 1));
    poll8(f_rh, (unsigned)(t + 1));
    stage(rp, (const char*)(rh + (size_t)mt * 16 * NH), 1024);
    __syncthreads();
    // ---- phase 2: h_tilde + combine (r/h-waves)
    if (!is_u) {
      f32x4 acc = {0.f, 0.f, 0.f, 0.f};
#pragma unroll
      for (int k4 = 0; k4 < 4; k4++) {
        bf16x8s w0 = *(const bf16x8s*)(wxB + (k4 * 4 + 0) * 32);
        bf16x8s w1 = *(const bf16x8s*)(wxB + (k4 * 4 + 1) * 32);
        bf16x8s w2 = *(const bf16x8s*)(wxB + (k4 * 4 + 2) * 32);
        bf16x8s w3 = *(const bf16x8s*)(wxB + (k4 * 4 + 3) * 32);
        acc = mfma16(afrag(rp, k4 * 4 + 0), bwB[k4 * 4 + 0], acc);
        acc = mfma16(afrag(rp, k4 * 4 + 1), bwB[k4 * 4 + 1], acc);
        acc = mfma16(afrag(rp, k4 * 4 + 2), bwB[k4 * 4 + 2], acc);
        acc = mfma16(afrag(rp, k4 * 4 + 3), bwB[k4 * 4 + 3], acc);
        acc = mfma16(afrag(xp, k4 * 4 + 0), w0, acc);
        acc = mfma16(afrag(xp, k4 * 4 + 1), w1, acc);
        acc = mfma16(afrag(xp, k4 * 4 + 2), w2, acc);
        acc = mfma16(afrag(xp, k4 * 4 + 3), w3, acc);
      }
#pragma unroll
      for (int j = 0; j < 4; j++) {
        int b = mt * 16 + g * 4 + j;
        float htil = tanhf(acc[j] + bB);
        float u = ul[(g * 4 + j) * 64 + wsub * 16 + cl];
        float hnew = h_reg[j] * u + (1.f - u) * htil;
        h_reg[j] = hnew;
        bf16 hn = f2bf(hnew);
        stus_sc((void*)(seql + ((size_t)b * NS + t) * NH + c), *(unsigned short*)&hn);
      }
    }
    publish(f_h, (unsigned)(t + 1));
  }
}

// ---------------- logits = seq1 @ w_out + b_out, depth-1 reg prefetch ----------------
__global__ void k_gemm_out(const bf16* __restrict__ A, const bf16* __restrict__ BT,
                           const float* __restrict__ bias, float* __restrict__ out) {
  int wid = blockIdx.x * 4 + (threadIdx.x >> 6);
  int mg = wid % 32, ng = wid / 32;
  int lane = threadIdx.x & 63;
  int cl = lane & 15, g = lane >> 4;
  f32x4 acc[4][4] = {};
  const bf16* a0 = A + (size_t)(mg * 64 + cl) * NE + g * 8;
  const bf16* b0 = BT + (size_t)(ng * 64 + cl) * NE + g * 8;
  bf16x8s av[2][4], bv[2][4];
#pragma unroll
  for (int i = 0; i < 4; i++) {
    av[0][i] = *(const bf16x8s*)(a0 + (size_t)(i * 16) * NE);
    bv[0][i] = *(const bf16x8s*)(b0 + (size_t)(i * 16) * NE);
  }
#pragma unroll
  for (int ks = 0; ks < 16; ks++) {
    const int cur = ks & 1;
    if (ks < 15) {
#pragma unroll
      for (int i = 0; i < 4; i++) {
        av[cur ^ 1][i] = *(const bf16x8s*)(a0 + (size_t)(i * 16) * NE + (ks + 1) * 32);
        bv[cur ^ 1][i] = *(const bf16x8s*)(b0 + (size_t)(i * 16) * NE + (ks + 1) * 32);
      }
    }
#pragma unroll
    for (int mi = 0; mi < 4; mi++)
#pragma unroll
      for (int ni = 0; ni < 4; ni++)
        acc[mi][ni] = mfma16(av[cur][mi], bv[cur][ni], acc[mi][ni]);
  }
#pragma unroll
  for (int mi = 0; mi < 4; mi++) {
#pragma unroll
    for (int ni = 0; ni < 4; ni++) {
      int colb = ng * 64 + ni * 16 + cl;
      if (colb < NV) {
        float bv2 = bias[colb];
#pragma unroll
        for (int j = 0; j < 4; j++) {
          int row = mg * 64 + mi * 16 + g * 4 + j;
          out[(size_t)row * NV + colb] = acc[mi][ni][j] + bv2;
        }
      }
    }
  }
}

extern "C" void kernel_launch(void* const* d_in, const int* in_sizes, int n_in,
                              void* d_out, int out_size, void* d_ws, size_t ws_size,
                              hipStream_t stream) {
  const int*   tokens = (const int*)d_in[0];
  const float* cnn    = (const float*)d_in[1];
  const float* emb    = (const float*)d_in[2];
  const float* w_in   = (const float*)d_in[3];
  const float* b_in   = (const float*)d_in[4];
  const float* w_r    = (const float*)d_in[5];
  const float* b_r    = (const float*)d_in[6];
  const float* w_u    = (const float*)d_in[7];
  const float* b_u    = (const float*)d_in[8];
  const float* w_h    = (const float*)d_in[9];
  const float* b_h    = (const float*)d_in[10];
  const float* w_out  = (const float*)d_in[11];
  const float* b_out  = (const float*)d_in[12];
  float* out = (float*)d_out;

  char* ws = (char*)d_ws;
  size_t off = 0;
  auto alloc = [&](size_t bytes) { char* p = ws + off; off += (bytes + 255) & ~(size_t)255; return p; };
  bf16*  x0      = (bf16*) alloc((size_t)2048 * 512 * 2);
  bf16*  seq0    = (bf16*) alloc((size_t)2048 * 512 * 2);
  bf16*  seq1    = (bf16*) alloc((size_t)2048 * 512 * 2);
  float* h0f     = (float*)alloc((size_t)64 * 512 * 4);
  bf16*  h0b     = (bf16*) alloc((size_t)64 * 512 * 2);
  bf16*  rh_all  = (bf16*) alloc((size_t)2 * 64 * 512 * 2);
  float* bias3   = (float*)alloc((size_t)2 * 1536 * 4);
  bf16*  cnn_b   = (bf16*) alloc((size_t)64 * 2048 * 2);
  bf16*  w_in_T  = (bf16*) alloc((size_t)512 * 2048 * 2);
  bf16*  w_ruh_T = (bf16*) alloc((size_t)2 * 1024 * 512 * 2);
  bf16*  w_hh_T  = (bf16*) alloc((size_t)2 * 512 * 512 * 2);
  bf16*  w_x_T   = (bf16*) alloc((size_t)2 * 1536 * 512 * 2);
  bf16*  w_out_T = (bf16*) alloc((size_t)10048 * 512 * 2);
  unsigned* flags = (unsigned*)alloc(2048);   // [2][4][2][32] u32
  (void)ws_size; (void)in_sizes; (void)n_in; (void)out_size;

  hipMemsetAsync(flags, 0, 2048, stream);
  hipMemsetAsync(w_out_T + (size_t)10000 * 512, 0, (size_t)48 * 512 * 2, stream);

  k_embed<<<2048, 256, 0, stream>>>(tokens, emb, x0);
  k_cvt<<<512, 256, 0, stream>>>(cnn, cnn_b, 64 * 2048);
  k_transpose<<<dim3(16, 64), 256, 0, stream>>>(w_in, w_in_T, NF, NH);
  k_transpose12<<<dim3(16, 16, 12), 256, 0, stream>>>(w_r, w_u, w_h, w_ruh_T, w_hh_T, w_x_T);
  k_transpose<<<dim3(313, 16), 256, 0, stream>>>(w_out, w_out_T, 512, NV);
  k_bias3all<<<12, 256, 0, stream>>>(b_r, b_u, b_h, bias3);

  k_gemm_h0<<<32, 256, 0, stream>>>(cnn_b, w_in_T, b_in, h0f, h0b);

  k_gru_fused<<<64, 512, 0, stream>>>(w_ruh_T, w_hh_T, w_x_T, bias3, h0f, h0b,
                                      x0, seq0, seq1, rh_all, flags);

  k_gemm_out<<<1256, 256, 0, stream>>>(seq1, w_out_T, b_out, out);
}